// Round 4
// baseline (172.621 us; speedup 1.0000x reference)
//
#include <hip/hip_runtime.h>
#include <math.h>

constexpr int kNumSeqs      = 64;
constexpr int kNumHeads     = 32;
constexpr int kNumKVHeads   = 8;
constexpr int kHeadDim      = 128;
constexpr int kGQA          = 4;       // 32/8
constexpr int kKVBlock      = 16;
constexpr int kMaxSeqlen    = 1024;
constexpr int kBlocksPerSeq = 64;
constexpr int kPart         = 4;       // split-K partitions
constexpr int kPartSize     = 256;     // positions per partition (== blockDim)
constexpr float kScale      = 0.08838834764831845f;  // 1/sqrt(128)
constexpr float kEps        = 1e-6f;

// ws layout (floats):
//   acc : [s][h][part][g][128] -> 1,048,576
//   m   : [s][h][part][g]      -> 8,192
//   l   : [s][h][part][g]      -> 8,192
constexpr size_t kAccElems = (size_t)kNumSeqs * kNumKVHeads * kPart * kGQA * kHeadDim;
constexpr size_t kMOff     = kAccElems;
constexpr size_t kLOff     = kAccElems + (size_t)kNumSeqs * kNumKVHeads * kPart * kGQA;

__launch_bounds__(256)
__global__ void paged_attn_part(
    const float* __restrict__ q,
    const float* __restrict__ k,
    const float* __restrict__ v,
    const float* __restrict__ k_cache,
    const float* __restrict__ v_cache,
    const float* __restrict__ qw,
    const float* __restrict__ kw,
    const float* __restrict__ cos_cache,
    const float* __restrict__ sin_cache,
    const int*   __restrict__ position,
    const int*   __restrict__ block_tables,
    const int*   __restrict__ context_lens,
    float* __restrict__ ws)
{
  const int bx   = blockIdx.x;
  const int s    = bx >> 5;
  const int h    = (bx >> 2) & 7;
  const int part = bx & 3;
  const int tid  = threadIdx.x;
  const int wave = tid >> 6;
  const int lane = tid & 63;

  const int ctx = context_lens[s];
  const int pos = position[s];                 // == ctx-1
  const int n0  = part * kPartSize;

  float* accw = ws + ((((size_t)s * kNumKVHeads + h) * kPart + part) * kGQA) * kHeadDim;
  float* mw   = ws + kMOff + (((size_t)s * kNumKVHeads + h) * kPart + part) * kGQA;
  float* lw   = ws + kLOff + (((size_t)s * kNumKVHeads + h) * kPart + part) * kGQA;

  if (n0 >= ctx) {                              // empty partition: neutral element
    for (int e = tid; e < kGQA * kHeadDim; e += 256) accw[e] = 0.0f;
    if (tid < kGQA) { mw[tid] = -3.0e38f; lw[tid] = 0.0f; }
    return;
  }
  const int cnt      = min(n0 + kPartSize, ctx) - n0;   // 1..256
  const int posLocal = pos - n0;
  const bool haspos  = (posLocal >= 0) && (posLocal < cnt);

  __shared__ __align__(16) float sc2[kPartSize][kGQA];    // probs, position-major
  __shared__ __align__(16) float q_lds[kGQA][kHeadDim];
  __shared__ __align__(16) float kn_lds[kHeadDim];
  __shared__ __align__(16) float vn_lds[kHeadDim];
  __shared__ int   bt_lds[kPartSize / kKVBlock];          // 16 blocks
  __shared__ float red[4][kGQA];
  __shared__ float mfin[kGQA];
  __shared__ float lfin[kGQA];
  __shared__ __align__(16) float outp[4][kGQA][kHeadDim];

  // ---------------- prologue: RMSNorm + RoPE, stage new k/v + block table ----------------
  {
    const int g = wave;
    const float* qrow = q + (size_t)s * (kNumHeads * kHeadDim) + (h * kGQA + g) * kHeadDim;
    float x1 = qrow[lane];
    float x2 = qrow[lane + 64];
    float ss = x1 * x1 + x2 * x2;
    for (int off = 32; off >= 1; off >>= 1) ss += __shfl_xor(ss, off);
    const float r = rsqrtf(ss * (1.0f / kHeadDim) + kEps);
    x1 *= r * qw[lane];
    x2 *= r * qw[lane + 64];
    const float c  = cos_cache[pos * 64 + lane];
    const float sn = sin_cache[pos * 64 + lane];
    q_lds[g][lane]      = (x1 * c - x2 * sn) * kScale;
    q_lds[g][lane + 64] = (x2 * c + x1 * sn) * kScale;
  }
  if (wave == 0) {
    const float* krow = k + (size_t)s * (kNumKVHeads * kHeadDim) + h * kHeadDim;
    float x1 = krow[lane];
    float x2 = krow[lane + 64];
    float ss = x1 * x1 + x2 * x2;
    for (int off = 32; off >= 1; off >>= 1) ss += __shfl_xor(ss, off);
    const float r = rsqrtf(ss * (1.0f / kHeadDim) + kEps);
    x1 *= r * kw[lane];
    x2 *= r * kw[lane + 64];
    const float c  = cos_cache[pos * 64 + lane];
    const float sn = sin_cache[pos * 64 + lane];
    kn_lds[lane]      = x1 * c - x2 * sn;
    kn_lds[lane + 64] = x2 * c + x1 * sn;
  } else if (wave == 1) {
    const float* vrow = v + (size_t)s * (kNumKVHeads * kHeadDim) + h * kHeadDim;
    vn_lds[lane]      = vrow[lane];
    vn_lds[lane + 64] = vrow[lane + 64];
  } else if (wave == 2) {
    if (lane < kPartSize / kKVBlock)
      bt_lds[lane] = block_tables[s * kBlocksPerSeq + part * (kPartSize / kKVBlock) + lane];
  }
  __syncthreads();   // B1

  // ---------------- pass 1: lane-per-position QK (no shuffles in the dot) ----------------
  const int  nl    = tid;                      // local position owned by this lane
  const bool validn = (nl < cnt);
  const int  nn    = validn ? nl : (cnt - 1);
  const bool ispos = haspos && (nn == posLocal);
  {
    const int blk = bt_lds[nn >> 4];
    const float* krow =
        k_cache + (((size_t)blk * kKVBlock + (nn & 15)) * kNumKVHeads + h) * kHeadDim;

    float sg[kGQA] = {0.f, 0.f, 0.f, 0.f};
    #pragma unroll 8
    for (int c = 0; c < 32; ++c) {
      float4 kv = *(const float4*)(krow + 4 * c);
      const float4 knc = *(const float4*)&kn_lds[4 * c];
      if (ispos) kv = knc;                     // virtual cache insert (new k)
      #pragma unroll
      for (int g = 0; g < kGQA; ++g) {
        const float4 qc = *(const float4*)&q_lds[g][4 * c];
        sg[g] += qc.x * kv.x + qc.y * kv.y + qc.z * kv.z + qc.w * kv.w;
      }
    }
    if (!validn) {
      #pragma unroll
      for (int g = 0; g < kGQA; ++g) sg[g] = -3.0e38f;
    }

    // wave max (one 6-step butterfly per g, once per 64 positions)
    float mg[kGQA];
    #pragma unroll
    for (int g = 0; g < kGQA; ++g) mg[g] = sg[g];
    #pragma unroll
    for (int off = 32; off >= 1; off >>= 1) {
      #pragma unroll
      for (int g = 0; g < kGQA; ++g) mg[g] = fmaxf(mg[g], __shfl_xor(mg[g], off));
    }
    if (lane == 0) {
      #pragma unroll
      for (int g = 0; g < kGQA; ++g) red[wave][g] = mg[g];
    }
    __syncthreads();   // B2
    if (tid < kGQA) {
      float m = red[0][tid];
      #pragma unroll
      for (int w = 1; w < 4; ++w) m = fmaxf(m, red[w][tid]);
      mfin[tid] = m;
    }
    __syncthreads();   // B3

    // exp, stash probs position-major (one ds_write_b128 per lane), wave sum
    float p[kGQA], lg[kGQA];
    #pragma unroll
    for (int g = 0; g < kGQA; ++g) {
      p[g]  = __expf(sg[g] - mfin[g]);         // invalid lanes -> 0
      lg[g] = p[g];
    }
    *(float4*)&sc2[nl][0] = make_float4(p[0], p[1], p[2], p[3]);
    #pragma unroll
    for (int off = 32; off >= 1; off >>= 1) {
      #pragma unroll
      for (int g = 0; g < kGQA; ++g) lg[g] += __shfl_xor(lg[g], off);
    }
    if (lane == 0) {
      #pragma unroll
      for (int g = 0; g < kGQA; ++g) red[wave][g] = lg[g];
    }
  }
  __syncthreads();   // B4 (sc2 + red complete)
  if (tid < kGQA) {
    float t = 0.0f;
    #pragma unroll
    for (int w = 0; w < 4; ++w) t += red[w][tid];
    lfin[tid] = t;                              // consumed after B5
  }

  // ---------------- pass 2: probs @ V (dim-major, coalesced) ----------------
  const int half = lane >> 5;
  const int l    = lane & 31;
  const int npairs = (cnt + 1) >> 1;
  const int ppw    = (npairs + 3) >> 2;
  const int pbeg   = wave * ppw;
  const int pend   = min(pbeg + ppw, npairs);

  float4 acc[kGQA];
  #pragma unroll
  for (int g = 0; g < kGQA; ++g) acc[g] = make_float4(0.f, 0.f, 0.f, 0.f);
  #pragma unroll 2
  for (int p = pbeg; p < pend; ++p) {
    const int  nl2 = 2 * p + half;
    const int  nn2 = (nl2 < cnt) ? nl2 : (cnt - 1);
    const int  blk = bt_lds[nn2 >> 4];
    const float* vrow =
        v_cache + (((size_t)blk * kKVBlock + (nn2 & 15)) * kNumKVHeads + h) * kHeadDim;
    float4 vv = *(const float4*)(vrow + 4 * l);
    if (haspos && nn2 == posLocal) vv = *(const float4*)&vn_lds[4 * l];  // virtual insert
    const float4 pr = *(const float4*)&sc2[nl2][0];   // p==0 for invalid positions
    acc[0].x += pr.x * vv.x; acc[0].y += pr.x * vv.y; acc[0].z += pr.x * vv.z; acc[0].w += pr.x * vv.w;
    acc[1].x += pr.y * vv.x; acc[1].y += pr.y * vv.y; acc[1].z += pr.y * vv.z; acc[1].w += pr.y * vv.w;
    acc[2].x += pr.z * vv.x; acc[2].y += pr.z * vv.y; acc[2].z += pr.z * vv.z; acc[2].w += pr.z * vv.w;
    acc[3].x += pr.w * vv.x; acc[3].y += pr.w * vv.y; acc[3].z += pr.w * vv.z; acc[3].w += pr.w * vv.w;
  }
  #pragma unroll
  for (int g = 0; g < kGQA; ++g) {
    acc[g].x += __shfl_xor(acc[g].x, 32);
    acc[g].y += __shfl_xor(acc[g].y, 32);
    acc[g].z += __shfl_xor(acc[g].z, 32);
    acc[g].w += __shfl_xor(acc[g].w, 32);
  }
  if (half == 0) {
    #pragma unroll
    for (int g = 0; g < kGQA; ++g)
      *(float4*)&outp[wave][g][4 * l] = acc[g];
  }
  __syncthreads();   // B5

  // ---------------- emit partials ----------------
  for (int e = tid; e < kGQA * kHeadDim; e += 256) {
    const int g = e >> 7;
    const int d = e & 127;
    float sum = 0.0f;
    #pragma unroll
    for (int w = 0; w < 4; ++w) sum += outp[w][g][d];
    accw[e] = sum;
  }
  if (tid < kGQA) { mw[tid] = mfin[tid]; lw[tid] = lfin[tid]; }
}

__launch_bounds__(128)
__global__ void paged_attn_reduce(const float* __restrict__ ws,
                                  float* __restrict__ out)
{
  const int idx = blockIdx.x;          // (s*8+h)*4 + g
  const int g   = idx & 3;
  const int sh  = idx >> 2;
  const int d   = threadIdx.x;

  const float* mw = ws + kMOff + (size_t)sh * (kPart * kGQA);
  const float* lw = ws + kLOff + (size_t)sh * (kPart * kGQA);

  float m[kPart];
  #pragma unroll
  for (int p = 0; p < kPart; ++p) m[p] = mw[p * kGQA + g];
  float mstar = m[0];
  #pragma unroll
  for (int p = 1; p < kPart; ++p) mstar = fmaxf(mstar, m[p]);

  float w[kPart], lstar = 0.0f;
  #pragma unroll
  for (int p = 0; p < kPart; ++p) {
    w[p] = __expf(m[p] - mstar);
    lstar += w[p] * lw[p * kGQA + g];
  }

  float o = 0.0f;
  #pragma unroll
  for (int p = 0; p < kPart; ++p) {
    const float* accp = ws + (((size_t)sh * kPart + p) * kGQA + g) * kHeadDim;
    o += w[p] * accp[d];
  }
  const int s = sh >> 3, h = sh & 7;
  out[(size_t)s * (kNumHeads * kHeadDim) + (h * kGQA + g) * kHeadDim + d] = o / lstar;
}

extern "C" void kernel_launch(void* const* d_in, const int* in_sizes, int n_in,
                              void* d_out, int out_size, void* d_ws, size_t ws_size,
                              hipStream_t stream) {
  const float* q            = (const float*)d_in[0];
  const float* k            = (const float*)d_in[1];
  const float* v            = (const float*)d_in[2];
  const float* k_cache      = (const float*)d_in[3];
  const float* v_cache      = (const float*)d_in[4];
  const float* qw           = (const float*)d_in[5];
  const float* kw           = (const float*)d_in[6];
  const float* cosc         = (const float*)d_in[7];
  const float* sinc         = (const float*)d_in[8];
  const int*   position     = (const int*)d_in[9];
  const int*   block_tables = (const int*)d_in[11];
  const int*   context_lens = (const int*)d_in[12];
  float* out                = (float*)d_out;
  float* ws                 = (float*)d_ws;

  hipLaunchKernelGGL(paged_attn_part, dim3(kNumSeqs * kNumKVHeads * kPart), dim3(256),
                     0, stream,
                     q, k, v, k_cache, v_cache, qw, kw, cosc, sinc,
                     position, block_tables, context_lens, ws);
  hipLaunchKernelGGL(paged_attn_reduce, dim3(kNumSeqs * kNumKVHeads * kGQA), dim3(kHeadDim),
                     0, stream, ws, out);
}

// Round 5
// 99.255 us; speedup vs baseline: 1.7392x; 1.7392x over previous
//
#include <hip/hip_runtime.h>
#include <math.h>

constexpr int kNumSeqs      = 64;
constexpr int kNumHeads     = 32;
constexpr int kNumKVHeads   = 8;
constexpr int kHeadDim      = 128;
constexpr int kGQA          = 4;       // 32/8
constexpr int kKVBlock      = 16;
constexpr int kMaxSeqlen    = 1024;
constexpr int kBlocksPerSeq = 64;
constexpr int kPart         = 4;       // split-K partitions
constexpr int kPartSize     = 256;     // positions per partition
constexpr float kScale      = 0.08838834764831845f;  // 1/sqrt(128)
constexpr float kEps        = 1e-6f;

constexpr size_t kAccElems = (size_t)kNumSeqs * kNumKVHeads * kPart * kGQA * kHeadDim;
constexpr size_t kMOff     = kAccElems;
constexpr size_t kLOff     = kAccElems + (size_t)kNumSeqs * kNumKVHeads * kPart * kGQA;

__launch_bounds__(256)
__global__ void paged_attn_part(
    const float* __restrict__ q,
    const float* __restrict__ k,
    const float* __restrict__ v,
    const float* __restrict__ k_cache,
    const float* __restrict__ v_cache,
    const float* __restrict__ qw,
    const float* __restrict__ kw,
    const float* __restrict__ cos_cache,
    const float* __restrict__ sin_cache,
    const int*   __restrict__ position,
    const int*   __restrict__ block_tables,
    const int*   __restrict__ context_lens,
    float* __restrict__ ws)
{
  const int bx   = blockIdx.x;
  const int s    = bx >> 5;
  const int h    = (bx >> 2) & 7;
  const int part = bx & 3;
  const int tid  = threadIdx.x;
  const int wave = tid >> 6;
  const int lane = tid & 63;

  const int ctx = context_lens[s];
  const int pos = position[s];                 // == ctx-1
  const int n0  = part * kPartSize;

  float* accw = ws + ((((size_t)s * kNumKVHeads + h) * kPart + part) * kGQA) * kHeadDim;
  float* mw   = ws + kMOff + (((size_t)s * kNumKVHeads + h) * kPart + part) * kGQA;
  float* lw   = ws + kLOff + (((size_t)s * kNumKVHeads + h) * kPart + part) * kGQA;

  if (n0 >= ctx) {                              // empty partition: neutral element
    for (int e = tid; e < kGQA * kHeadDim; e += 256) accw[e] = 0.0f;
    if (tid < kGQA) { mw[tid] = -3.0e38f; lw[tid] = 0.0f; }
    return;
  }
  const int cnt      = min(n0 + kPartSize, ctx) - n0;   // 1..256
  const int posLocal = pos - n0;
  const bool haspos  = (posLocal >= 0) && (posLocal < cnt);

  __shared__ __align__(16) float sc2[kPartSize][kGQA];    // scores -> probs (position-major)
  __shared__ __align__(16) float q_lds[kGQA][kHeadDim];
  __shared__ __align__(16) float kn_lds[kHeadDim];
  __shared__ __align__(16) float vn_lds[kHeadDim];
  __shared__ int   bt_lds[kPartSize / kKVBlock];          // 16 blocks
  __shared__ float red[4][kGQA];
  __shared__ float mfin[kGQA];
  __shared__ float lfin[kGQA];
  __shared__ __align__(16) float outp[4][kGQA][kHeadDim];

  // ---------------- prologue: RMSNorm + RoPE, stage new k/v + block table ----------------
  {
    const int g = wave;
    const float* qrow = q + (size_t)s * (kNumHeads * kHeadDim) + (h * kGQA + g) * kHeadDim;
    float x1 = qrow[lane];
    float x2 = qrow[lane + 64];
    float ss = x1 * x1 + x2 * x2;
    for (int off = 32; off >= 1; off >>= 1) ss += __shfl_xor(ss, off);
    const float r = rsqrtf(ss * (1.0f / kHeadDim) + kEps);
    x1 *= r * qw[lane];
    x2 *= r * qw[lane + 64];
    const float c  = cos_cache[pos * 64 + lane];
    const float sn = sin_cache[pos * 64 + lane];
    q_lds[g][lane]      = (x1 * c - x2 * sn) * kScale;
    q_lds[g][lane + 64] = (x2 * c + x1 * sn) * kScale;
  }
  if (wave == 0) {
    const float* krow = k + (size_t)s * (kNumKVHeads * kHeadDim) + h * kHeadDim;
    float x1 = krow[lane];
    float x2 = krow[lane + 64];
    float ss = x1 * x1 + x2 * x2;
    for (int off = 32; off >= 1; off >>= 1) ss += __shfl_xor(ss, off);
    const float r = rsqrtf(ss * (1.0f / kHeadDim) + kEps);
    x1 *= r * kw[lane];
    x2 *= r * kw[lane + 64];
    const float c  = cos_cache[pos * 64 + lane];
    const float sn = sin_cache[pos * 64 + lane];
    kn_lds[lane]      = x1 * c - x2 * sn;
    kn_lds[lane + 64] = x2 * c + x1 * sn;
  } else if (wave == 1) {
    const float* vrow = v + (size_t)s * (kNumKVHeads * kHeadDim) + h * kHeadDim;
    vn_lds[lane]      = vrow[lane];
    vn_lds[lane + 64] = vrow[lane + 64];
  } else if (wave == 2) {
    if (lane < kPartSize / kKVBlock)
      bt_lds[lane] = block_tables[s * kBlocksPerSeq + part * (kPartSize / kKVBlock) + lane];
  }
  __syncthreads();   // B1

  const int half = lane >> 5;       // which of the 2 positions in a pair
  const int l    = lane & 31;       // dim chunk: floats [4l, 4l+4)

  float4 qf[kGQA];
  #pragma unroll
  for (int g = 0; g < kGQA; ++g)
    qf[g] = *(const float4*)&q_lds[g][4 * l];
  const float4 knc = *(const float4*)&kn_lds[4 * l];
  const float4 vnc = *(const float4*)&vn_lds[4 * l];

  const int npairs = (cnt + 1) >> 1;   // 1..128

  // ---------------- pass 1: batched coalesced QK (4 pairs in flight / wave) ----------------
  for (int b = 0; wave + 16 * b < npairs; ++b) {
    float4 kv[4];
    int    nls[4];
    bool   val[4];
    #pragma unroll
    for (int jj = 0; jj < 4; ++jj) {
      const int  p  = wave + 16 * b + 4 * jj;
      const bool pv = (p < npairs);
      const int  pp = pv ? p : (npairs - 1);
      const int  n  = 2 * pp + half;
      const bool v  = pv && (n < cnt);
      const int  nn = (n < cnt) ? n : (cnt - 1);
      nls[jj] = n;
      val[jj] = v;
      const int blk = bt_lds[nn >> 4];
      const float* krow =
          k_cache + (((size_t)blk * kKVBlock + (nn & 15)) * kNumKVHeads + h) * kHeadDim;
      kv[jj] = *(const float4*)(krow + 4 * l);
      if (haspos && nn == posLocal) kv[jj] = knc;   // virtual cache insert (new k)
    }
    float sg[4][kGQA];
    #pragma unroll
    for (int jj = 0; jj < 4; ++jj) {
      #pragma unroll
      for (int g = 0; g < kGQA; ++g)
        sg[jj][g] = qf[g].x * kv[jj].x + qf[g].y * kv[jj].y +
                    qf[g].z * kv[jj].z + qf[g].w * kv[jj].w;
    }
    #pragma unroll
    for (int off = 16; off >= 1; off >>= 1) {
      #pragma unroll
      for (int jj = 0; jj < 4; ++jj) {
        #pragma unroll
        for (int g = 0; g < kGQA; ++g) sg[jj][g] += __shfl_xor(sg[jj][g], off);
      }
    }
    #pragma unroll
    for (int jj = 0; jj < 4; ++jj) {
      if (l == 0 && val[jj])
        *(float4*)&sc2[nls[jj]][0] =
            make_float4(sg[jj][0], sg[jj][1], sg[jj][2], sg[jj][3]);
    }
  }
  __syncthreads();   // B2 (all scores in LDS)

  // ---------------- softmax: max (position-major, one entry per thread) ----------------
  float4 sv;
  if (tid < cnt) sv = *(const float4*)&sc2[tid][0];
  else           sv = make_float4(-3.0e38f, -3.0e38f, -3.0e38f, -3.0e38f);
  {
    float mg[kGQA] = {sv.x, sv.y, sv.z, sv.w};
    #pragma unroll
    for (int off = 32; off >= 1; off >>= 1) {
      #pragma unroll
      for (int g = 0; g < kGQA; ++g) mg[g] = fmaxf(mg[g], __shfl_xor(mg[g], off));
    }
    if (lane == 0) {
      #pragma unroll
      for (int g = 0; g < kGQA; ++g) red[wave][g] = mg[g];
    }
  }
  __syncthreads();   // B3
  if (tid < kGQA) {
    float m = red[0][tid];
    #pragma unroll
    for (int w = 1; w < 4; ++w) m = fmaxf(m, red[w][tid]);
    mfin[tid] = m;
  }
  __syncthreads();   // B4

  // ---------------- softmax: exp + sum (writes all 256 entries; tail -> 0) ----------------
  {
    float4 pv4;
    pv4.x = __expf(sv.x - mfin[0]);
    pv4.y = __expf(sv.y - mfin[1]);
    pv4.z = __expf(sv.z - mfin[2]);
    pv4.w = __expf(sv.w - mfin[3]);
    *(float4*)&sc2[tid][0] = pv4;
    float lg[kGQA] = {pv4.x, pv4.y, pv4.z, pv4.w};
    #pragma unroll
    for (int off = 32; off >= 1; off >>= 1) {
      #pragma unroll
      for (int g = 0; g < kGQA; ++g) lg[g] += __shfl_xor(lg[g], off);
    }
    if (lane == 0) {
      #pragma unroll
      for (int g = 0; g < kGQA; ++g) red[wave][g] = lg[g];
    }
  }
  __syncthreads();   // B5 (probs + red complete)
  if (tid < kGQA) {
    float t = 0.0f;
    #pragma unroll
    for (int w = 0; w < 4; ++w) t += red[w][tid];
    lfin[tid] = t;                              // consumed after B6
  }

  // ---------------- pass 2: batched coalesced PV (4 pairs in flight / wave) ----------------
  float4 acc[kGQA];
  #pragma unroll
  for (int g = 0; g < kGQA; ++g) acc[g] = make_float4(0.f, 0.f, 0.f, 0.f);
  for (int b = 0; wave + 16 * b < npairs; ++b) {
    float4 vv[4];
    float4 pr[4];
    #pragma unroll
    for (int jj = 0; jj < 4; ++jj) {
      const int  p  = wave + 16 * b + 4 * jj;
      const bool pv = (p < npairs);
      const int  pp = pv ? p : (npairs - 1);
      const int  n  = 2 * pp + half;              // <= cnt (tail prob already 0)
      const int  nn = (n < cnt) ? n : (cnt - 1);
      const int  blk = bt_lds[nn >> 4];
      const float* vrow =
          v_cache + (((size_t)blk * kKVBlock + (nn & 15)) * kNumKVHeads + h) * kHeadDim;
      vv[jj] = *(const float4*)(vrow + 4 * l);
      if (haspos && nn == posLocal) vv[jj] = vnc;  // virtual cache insert (new v)
      pr[jj] = pv ? *(const float4*)&sc2[n][0] : make_float4(0.f, 0.f, 0.f, 0.f);
    }
    #pragma unroll
    for (int jj = 0; jj < 4; ++jj) {
      acc[0].x += pr[jj].x * vv[jj].x; acc[0].y += pr[jj].x * vv[jj].y;
      acc[0].z += pr[jj].x * vv[jj].z; acc[0].w += pr[jj].x * vv[jj].w;
      acc[1].x += pr[jj].y * vv[jj].x; acc[1].y += pr[jj].y * vv[jj].y;
      acc[1].z += pr[jj].y * vv[jj].z; acc[1].w += pr[jj].y * vv[jj].w;
      acc[2].x += pr[jj].z * vv[jj].x; acc[2].y += pr[jj].z * vv[jj].y;
      acc[2].z += pr[jj].z * vv[jj].z; acc[2].w += pr[jj].z * vv[jj].w;
      acc[3].x += pr[jj].w * vv[jj].x; acc[3].y += pr[jj].w * vv[jj].y;
      acc[3].z += pr[jj].w * vv[jj].z; acc[3].w += pr[jj].w * vv[jj].w;
    }
  }
  #pragma unroll
  for (int g = 0; g < kGQA; ++g) {
    acc[g].x += __shfl_xor(acc[g].x, 32);
    acc[g].y += __shfl_xor(acc[g].y, 32);
    acc[g].z += __shfl_xor(acc[g].z, 32);
    acc[g].w += __shfl_xor(acc[g].w, 32);
  }
  if (half == 0) {
    #pragma unroll
    for (int g = 0; g < kGQA; ++g)
      *(float4*)&outp[wave][g][4 * l] = acc[g];
  }
  __syncthreads();   // B6

  // ---------------- emit partials ----------------
  for (int e = tid; e < kGQA * kHeadDim; e += 256) {
    const int g = e >> 7;
    const int d = e & 127;
    float sum = 0.0f;
    #pragma unroll
    for (int w = 0; w < 4; ++w) sum += outp[w][g][d];
    accw[e] = sum;
  }
  if (tid < kGQA) { mw[tid] = mfin[tid]; lw[tid] = lfin[tid]; }
}

__launch_bounds__(128)
__global__ void paged_attn_reduce(const float* __restrict__ ws,
                                  float* __restrict__ out)
{
  const int idx = blockIdx.x;          // (s*8+h)*4 + g
  const int g   = idx & 3;
  const int sh  = idx >> 2;
  const int d   = threadIdx.x;

  const float* mw = ws + kMOff + (size_t)sh * (kPart * kGQA);
  const float* lw = ws + kLOff + (size_t)sh * (kPart * kGQA);

  float m[kPart];
  #pragma unroll
  for (int p = 0; p < kPart; ++p) m[p] = mw[p * kGQA + g];
  float mstar = m[0];
  #pragma unroll
  for (int p = 1; p < kPart; ++p) mstar = fmaxf(mstar, m[p]);

  float w[kPart], lstar = 0.0f;
  #pragma unroll
  for (int p = 0; p < kPart; ++p) {
    w[p] = __expf(m[p] - mstar);
    lstar += w[p] * lw[p * kGQA + g];
  }

  float o = 0.0f;
  #pragma unroll
  for (int p = 0; p < kPart; ++p) {
    const float* accp = ws + (((size_t)sh * kPart + p) * kGQA + g) * kHeadDim;
    o += w[p] * accp[d];
  }
  const int s = sh >> 3, h = sh & 7;
  out[(size_t)s * (kNumHeads * kHeadDim) + (h * kGQA + g) * kHeadDim + d] = o / lstar;
}

extern "C" void kernel_launch(void* const* d_in, const int* in_sizes, int n_in,
                              void* d_out, int out_size, void* d_ws, size_t ws_size,
                              hipStream_t stream) {
  const float* q            = (const float*)d_in[0];
  const float* k            = (const float*)d_in[1];
  const float* v            = (const float*)d_in[2];
  const float* k_cache      = (const float*)d_in[3];
  const float* v_cache      = (const float*)d_in[4];
  const float* qw           = (const float*)d_in[5];
  const float* kw           = (const float*)d_in[6];
  const float* cosc         = (const float*)d_in[7];
  const float* sinc         = (const float*)d_in[8];
  const int*   position     = (const int*)d_in[9];
  const int*   block_tables = (const int*)d_in[11];
  const int*   context_lens = (const int*)d_in[12];
  float* out                = (float*)d_out;
  float* ws                 = (float*)d_ws;

  hipLaunchKernelGGL(paged_attn_part, dim3(kNumSeqs * kNumKVHeads * kPart), dim3(256),
                     0, stream,
                     q, k, v, k_cache, v_cache, qw, kw, cosc, sinc,
                     position, block_tables, context_lens, ws);
  hipLaunchKernelGGL(paged_attn_reduce, dim3(kNumSeqs * kNumKVHeads * kGQA), dim3(kHeadDim),
                     0, stream, ws, out);
}

// Round 6
// 95.049 us; speedup vs baseline: 1.8161x; 1.0442x over previous
//
#include <hip/hip_runtime.h>
#include <math.h>

constexpr int kNumSeqs      = 64;
constexpr int kNumHeads     = 32;
constexpr int kNumKVHeads   = 8;
constexpr int kHeadDim      = 128;
constexpr int kGQA          = 4;       // 32/8
constexpr int kKVBlock      = 16;
constexpr int kMaxSeqlen    = 1024;
constexpr int kBlocksPerSeq = 64;
constexpr int kPart         = 4;       // split-K partitions
constexpr int kPartSize     = 256;     // positions per partition
constexpr float kScale      = 0.08838834764831845f;  // 1/sqrt(128)
constexpr float kEps        = 1e-6f;

constexpr size_t kAccElems = (size_t)kNumSeqs * kNumKVHeads * kPart * kGQA * kHeadDim;
constexpr size_t kMOff     = kAccElems;
constexpr size_t kLOff     = kAccElems + (size_t)kNumSeqs * kNumKVHeads * kPart * kGQA;

__launch_bounds__(256, 4)
__global__ void paged_attn_part(
    const float* __restrict__ q,
    const float* __restrict__ k,
    const float* __restrict__ v,
    const float* __restrict__ k_cache,
    const float* __restrict__ v_cache,
    const float* __restrict__ qw,
    const float* __restrict__ kw,
    const float* __restrict__ cos_cache,
    const float* __restrict__ sin_cache,
    const int*   __restrict__ position,
    const int*   __restrict__ block_tables,
    const int*   __restrict__ context_lens,
    float* __restrict__ ws)
{
  const int bx   = blockIdx.x;
  const int s    = bx >> 5;
  const int h    = (bx >> 2) & 7;
  const int part = bx & 3;
  const int tid  = threadIdx.x;
  const int wave = tid >> 6;
  const int lane = tid & 63;

  const int ctx = context_lens[s];
  const int pos = position[s];                 // == ctx-1
  const int n0  = part * kPartSize;

  float* accw = ws + ((((size_t)s * kNumKVHeads + h) * kPart + part) * kGQA) * kHeadDim;
  float* mw   = ws + kMOff + (((size_t)s * kNumKVHeads + h) * kPart + part) * kGQA;
  float* lw   = ws + kLOff + (((size_t)s * kNumKVHeads + h) * kPart + part) * kGQA;

  if (n0 >= ctx) {                              // empty partition: neutral element
    for (int e = tid; e < kGQA * kHeadDim; e += 256) accw[e] = 0.0f;
    if (tid < kGQA) { mw[tid] = -3.0e38f; lw[tid] = 0.0f; }
    return;
  }
  const int cnt      = min(n0 + kPartSize, ctx) - n0;   // 1..256
  const int posLocal = pos - n0;
  const bool haspos  = (posLocal >= 0) && (posLocal < cnt);

  __shared__ __align__(16) float q_lds[kGQA][kHeadDim];
  __shared__ __align__(16) float kn_lds[kHeadDim];
  __shared__ __align__(16) float vn_lds[kHeadDim];
  __shared__ int bt_lds[kPartSize / kKVBlock];          // 16 blocks
  __shared__ __align__(16) float macc[8][kGQA][kHeadDim];  // per half-wave partials (16 KB)
  __shared__ float mm[8][kGQA];
  __shared__ float ml[8][kGQA];

  // ---------------- prologue: RMSNorm + RoPE, stage new k/v + block table ----------------
  {
    const int g = wave;
    const float* qrow = q + (size_t)s * (kNumHeads * kHeadDim) + (h * kGQA + g) * kHeadDim;
    float x1 = qrow[lane];
    float x2 = qrow[lane + 64];
    float ss = x1 * x1 + x2 * x2;
    for (int off = 32; off >= 1; off >>= 1) ss += __shfl_xor(ss, off);
    const float r = rsqrtf(ss * (1.0f / kHeadDim) + kEps);
    x1 *= r * qw[lane];
    x2 *= r * qw[lane + 64];
    const float c  = cos_cache[pos * 64 + lane];
    const float sn = sin_cache[pos * 64 + lane];
    q_lds[g][lane]      = (x1 * c - x2 * sn) * kScale;
    q_lds[g][lane + 64] = (x2 * c + x1 * sn) * kScale;
  }
  if (wave == 0) {
    const float* krow = k + (size_t)s * (kNumKVHeads * kHeadDim) + h * kHeadDim;
    float x1 = krow[lane];
    float x2 = krow[lane + 64];
    float ss = x1 * x1 + x2 * x2;
    for (int off = 32; off >= 1; off >>= 1) ss += __shfl_xor(ss, off);
    const float r = rsqrtf(ss * (1.0f / kHeadDim) + kEps);
    x1 *= r * kw[lane];
    x2 *= r * kw[lane + 64];
    const float c  = cos_cache[pos * 64 + lane];
    const float sn = sin_cache[pos * 64 + lane];
    kn_lds[lane]      = x1 * c - x2 * sn;
    kn_lds[lane + 64] = x2 * c + x1 * sn;
  } else if (wave == 1) {
    const float* vrow = v + (size_t)s * (kNumKVHeads * kHeadDim) + h * kHeadDim;
    vn_lds[lane]      = vrow[lane];
    vn_lds[lane + 64] = vrow[lane + 64];
  } else if (wave == 2) {
    if (lane < kPartSize / kKVBlock)
      bt_lds[lane] = block_tables[s * kBlocksPerSeq + part * (kPartSize / kKVBlock) + lane];
  }
  __syncthreads();   // B1 (only mid-kernel barrier before the final merge)

  const int half = lane >> 5;       // which of the 2 positions in a pair
  const int l    = lane & 31;       // dim chunk: floats [4l, 4l+4)

  float4 qf[kGQA];
  #pragma unroll
  for (int g = 0; g < kGQA; ++g)
    qf[g] = *(const float4*)&q_lds[g][4 * l];

  const int npairs = (cnt + 1) >> 1;   // 1..128

  // ---------------- single-pass flash loop (4 pairs => 4 K-loads + 4 V-loads in flight) ----
  float mrun[kGQA], lrun[kGQA];
  float4 acc[kGQA];
  #pragma unroll
  for (int g = 0; g < kGQA; ++g) {
    mrun[g] = -3.0e38f; lrun[g] = 0.0f;
    acc[g] = make_float4(0.f, 0.f, 0.f, 0.f);
  }

  for (int b = 0; wave + 16 * b < npairs; ++b) {
    float4 kv[4], vv[4];
    bool   val[4];
    #pragma unroll
    for (int jj = 0; jj < 4; ++jj) {
      const int  p  = wave + 16 * b + 4 * jj;
      const bool pv = (p < npairs);
      const int  pp = pv ? p : (npairs - 1);
      const int  n  = 2 * pp + half;
      val[jj] = pv && (n < cnt);
      const int  nn = (n < cnt) ? n : (cnt - 1);
      const int  blk = bt_lds[nn >> 4];
      const size_t base = (((size_t)blk * kKVBlock + (nn & 15)) * kNumKVHeads + h) * kHeadDim;
      kv[jj] = *(const float4*)(k_cache + base + 4 * l);
      vv[jj] = *(const float4*)(v_cache + base + 4 * l);
      if (haspos && nn == posLocal) {            // virtual cache insert (new k/v)
        kv[jj] = *(const float4*)&kn_lds[4 * l];
        vv[jj] = *(const float4*)&vn_lds[4 * l];
      }
    }

    float sg[4][kGQA];
    #pragma unroll
    for (int jj = 0; jj < 4; ++jj) {
      #pragma unroll
      for (int g = 0; g < kGQA; ++g)
        sg[jj][g] = qf[g].x * kv[jj].x + qf[g].y * kv[jj].y +
                    qf[g].z * kv[jj].z + qf[g].w * kv[jj].w;
    }
    #pragma unroll
    for (int off = 16; off >= 1; off >>= 1) {
      #pragma unroll
      for (int jj = 0; jj < 4; ++jj) {
        #pragma unroll
        for (int g = 0; g < kGQA; ++g) sg[jj][g] += __shfl_xor(sg[jj][g], off);
      }
    }
    #pragma unroll
    for (int jj = 0; jj < 4; ++jj) {
      if (!val[jj]) {
        #pragma unroll
        for (int g = 0; g < kGQA; ++g) sg[jj][g] = -3.0e38f;
      }
    }

    // online softmax update, independent per half-wave
    #pragma unroll
    for (int g = 0; g < kGQA; ++g) {
      const float mb = fmaxf(fmaxf(sg[0][g], sg[1][g]), fmaxf(sg[2][g], sg[3][g]));
      const float mn = fmaxf(mrun[g], mb);
      const float f  = __expf(mrun[g] - mn);     // ==1 when unchanged; ==0 cleans stale
      const float p0 = __expf(sg[0][g] - mn);
      const float p1 = __expf(sg[1][g] - mn);
      const float p2 = __expf(sg[2][g] - mn);
      const float p3 = __expf(sg[3][g] - mn);
      lrun[g] = lrun[g] * f + (p0 + p1 + p2 + p3);
      acc[g].x = acc[g].x * f + p0 * vv[0].x + p1 * vv[1].x + p2 * vv[2].x + p3 * vv[3].x;
      acc[g].y = acc[g].y * f + p0 * vv[0].y + p1 * vv[1].y + p2 * vv[2].y + p3 * vv[3].y;
      acc[g].z = acc[g].z * f + p0 * vv[0].z + p1 * vv[1].z + p2 * vv[2].z + p3 * vv[3].z;
      acc[g].w = acc[g].w * f + p0 * vv[0].w + p1 * vv[1].w + p2 * vv[2].w + p3 * vv[3].w;
      mrun[g] = mn;
    }
  }

  // ---------------- stash 8 half-wave partials ----------------
  {
    const int idx = wave * 2 + half;
    #pragma unroll
    for (int g = 0; g < kGQA; ++g)
      *(float4*)&macc[idx][g][4 * l] = acc[g];
    if (l == 0) {
      #pragma unroll
      for (int g = 0; g < kGQA; ++g) { mm[idx][g] = mrun[g]; ml[idx][g] = lrun[g]; }
    }
  }
  __syncthreads();   // B2

  // ---------------- merge halves, emit partition partial ----------------
  for (int e = tid; e < kGQA * kHeadDim; e += 256) {
    const int g = e >> 7;
    const int d = e & 127;
    float ms = mm[0][g];
    #pragma unroll
    for (int i = 1; i < 8; ++i) ms = fmaxf(ms, mm[i][g]);
    float ls = 0.0f, o = 0.0f;
    #pragma unroll
    for (int i = 0; i < 8; ++i) {
      const float w = __expf(mm[i][g] - ms);
      ls += w * ml[i][g];
      o  += w * macc[i][g][d];
    }
    accw[e] = o;
    if (d == 0) { mw[g] = ms; lw[g] = ls; }
  }
}

__launch_bounds__(128)
__global__ void paged_attn_reduce(const float* __restrict__ ws,
                                  float* __restrict__ out)
{
  const int idx = blockIdx.x;          // (s*8+h)*4 + g
  const int g   = idx & 3;
  const int sh  = idx >> 2;
  const int d   = threadIdx.x;

  const float* mw = ws + kMOff + (size_t)sh * (kPart * kGQA);
  const float* lw = ws + kLOff + (size_t)sh * (kPart * kGQA);

  float m[kPart];
  #pragma unroll
  for (int p = 0; p < kPart; ++p) m[p] = mw[p * kGQA + g];
  float mstar = m[0];
  #pragma unroll
  for (int p = 1; p < kPart; ++p) mstar = fmaxf(mstar, m[p]);

  float w[kPart], lstar = 0.0f;
  #pragma unroll
  for (int p = 0; p < kPart; ++p) {
    w[p] = __expf(m[p] - mstar);
    lstar += w[p] * lw[p * kGQA + g];
  }

  float o = 0.0f;
  #pragma unroll
  for (int p = 0; p < kPart; ++p) {
    const float* accp = ws + (((size_t)sh * kPart + p) * kGQA + g) * kHeadDim;
    o += w[p] * accp[d];
  }
  const int s = sh >> 3, h = sh & 7;
  out[(size_t)s * (kNumHeads * kHeadDim) + (h * kGQA + g) * kHeadDim + d] = o / lstar;
}

extern "C" void kernel_launch(void* const* d_in, const int* in_sizes, int n_in,
                              void* d_out, int out_size, void* d_ws, size_t ws_size,
                              hipStream_t stream) {
  const float* q            = (const float*)d_in[0];
  const float* k            = (const float*)d_in[1];
  const float* v            = (const float*)d_in[2];
  const float* k_cache      = (const float*)d_in[3];
  const float* v_cache      = (const float*)d_in[4];
  const float* qw           = (const float*)d_in[5];
  const float* kw           = (const float*)d_in[6];
  const float* cosc         = (const float*)d_in[7];
  const float* sinc         = (const float*)d_in[8];
  const int*   position     = (const int*)d_in[9];
  const int*   block_tables = (const int*)d_in[11];
  const int*   context_lens = (const int*)d_in[12];
  float* out                = (float*)d_out;
  float* ws                 = (float*)d_ws;

  hipLaunchKernelGGL(paged_attn_part, dim3(kNumSeqs * kNumKVHeads * kPart), dim3(256),
                     0, stream,
                     q, k, v, k_cache, v_cache, qw, kw, cosc, sinc,
                     position, block_tables, context_lens, ws);
  hipLaunchKernelGGL(paged_attn_reduce, dim3(kNumSeqs * kNumKVHeads * kGQA), dim3(kHeadDim),
                     0, stream, ws, out);
}